// Round 3
// baseline (83.089 us; speedup 1.0000x reference)
//
#include <hip/hip_runtime.h>

// StateSpaceLayer: out[b,t,r,c] = sum_{j<=t} A[r]^(t-j) * x[b,j,r,c]
// == linear recurrence state[t] = A[r]*state[t-1] + x[t] along seq.
// Shapes: x (4,512,64,64) f32, A (64,) f32, out same. Memory-bound:
// 134 MB kernel traffic -> ~13 us at 6.3 TB/s. dur_us floor ~83 us is
// dominated by harness re-poison fills (268 MB writes @ 6.3 TB/s each
// iteration) -- two structurally different kernels timed within 4 ns.
//
// This variant maximizes MLP: 1024 threads (16 waves/CU) AND float4
// (16 B/lane), CHUNK=8 so local[8] float4 = 32 VGPRs fits the 128-VGPR
// cap at 4 waves/SIMD with all 8 loads clustered in flight
// (1024 lanes x 128 B = 128 KB/CU in flight >> ~22 KB needed for HBM).

#define B_      4
#define SEQ_    512
#define D_      64
#define CHUNK_  8
#define NCHUNK_ (SEQ_ / CHUNK_)   // 64 chunks
#define Q_      (D_ / 4)          // 16 float4 per (j,r) row

__global__ __launch_bounds__(NCHUNK_ * Q_) void ssm_scan_kernel(
    const float4* __restrict__ x, const float* __restrict__ A,
    float4* __restrict__ out)
{
    __shared__ float4 Elds[NCHUNK_][Q_];   // chunk-end states (16 KB)

    const int bi  = blockIdx.x >> 6;       // batch
    const int r   = blockIdx.x & 63;       // decay row (block-uniform)
    const int tid = threadIdx.x;
    const int w   = tid >> 4;              // chunk id 0..63
    const int q   = tid & 15;              // float4 column 0..15

    const float a = fmaxf(A[r], 1e-6f);    // block-uniform -> SGPR

    const int j0 = w * CHUNK_;
    // float4 index of x[bi, j, r, 4q] = ((bi*SEQ + j)*D + r)*Q + q
    const size_t  base    = ((size_t)(bi * SEQ_ + j0) * D_ + r) * Q_ + q;
    const float4* xp      = x + base;
    float4*       op      = out + base;
    const int     jstride = D_ * Q_;       // 1024 float4 between timesteps

    // Phase 1: local scan of this chunk, zero initial state.
    float4 local[CHUNK_];
    float4 s = make_float4(0.f, 0.f, 0.f, 0.f);
    #pragma unroll
    for (int t = 0; t < CHUNK_; ++t) {
        float4 v = xp[(size_t)t * jstride];
        s.x = fmaf(s.x, a, v.x);
        s.y = fmaf(s.y, a, v.y);
        s.z = fmaf(s.z, a, v.z);
        s.w = fmaf(s.w, a, v.w);
        local[t] = s;
    }

    Elds[w][q] = s;
    __syncthreads();

    // a^CHUNK_ (= a^8) via 3 squarings.
    float aL = a * a;   // a^2
    aL = aL * aL;       // a^4
    aL = aL * aL;       // a^8

    // Carry into this chunk: Horner over lower chunks' end states.
    float4 carry = make_float4(0.f, 0.f, 0.f, 0.f);
    for (int wp = 0; wp < w; ++wp) {
        float4 e = Elds[wp][q];
        carry.x = fmaf(carry.x, aL, e.x);
        carry.y = fmaf(carry.y, aL, e.y);
        carry.z = fmaf(carry.z, aL, e.z);
        carry.w = fmaf(carry.w, aL, e.w);
    }

    // Phase 3: out[j0+t] = local[t] + carry * a^(t+1), store float4.
    float p = a;
    #pragma unroll
    for (int t = 0; t < CHUNK_; ++t) {
        float4 o;
        o.x = fmaf(carry.x, p, local[t].x);
        o.y = fmaf(carry.y, p, local[t].y);
        o.z = fmaf(carry.z, p, local[t].z);
        o.w = fmaf(carry.w, p, local[t].w);
        op[(size_t)t * jstride] = o;
        p *= a;
    }
}

extern "C" void kernel_launch(void* const* d_in, const int* in_sizes, int n_in,
                              void* d_out, int out_size, void* d_ws, size_t ws_size,
                              hipStream_t stream) {
    const float4* x   = (const float4*)d_in[0];
    const float*  A   = (const float*)d_in[1];
    float4*       out = (float4*)d_out;

    dim3 grid(B_ * D_);              // 256 blocks, one per (batch, r)
    dim3 block(NCHUNK_ * Q_);        // 1024 threads = 16 waves
    hipLaunchKernelGGL(ssm_scan_kernel, grid, block, 0, stream, x, A, out);
}